// Round 1
// baseline (789.922 us; speedup 1.0000x reference)
//
#include <hip/hip_runtime.h>
#include <hip/hip_bf16.h>

// Problem constants (fixed by the reference)
#define NN 100000
#define EE 1600000
#define NODE_DIM 128
#define HID 64
#define NGRAPH 256
#define BN_EPS 1e-5f

// ---------------- workspace layout (units of 4 bytes) ----------------
#define I_DEG   0                         // int[NN]
#define I_OFF   100032                    // int[NN+1]
#define I_CUR   200064                    // int[NN]
#define I_BS    300096                    // int[128]
#define I_BO    300224                    // int[128]
#define I_SRC   300352                    // int[EE]
#define I_EW    1900352                   // float[EE]
#define I_DINV  3500352                   // float[NN]
#define I_WC    3600352                   // float[128*64 + 64]
#define I_BUFA  3608640                   // float[NN*64]
#define I_BUFB  10008640                  // float[NN*64]
// total = 16,408,640 * 4B = ~65.7 MB

// ---------------- graph prep ----------------

__global__ void count_k(const int* __restrict__ dst, int* __restrict__ cnt) {
    int e = blockIdx.x * 256 + threadIdx.x;   // grid exactly EE
    atomicAdd(&cnt[dst[e]], 1);
}

__global__ void dinv_k(const int* __restrict__ cnt, float* __restrict__ dinv, int n) {
    int i = blockIdx.x * 256 + threadIdx.x;
    if (i < n) dinv[i] = rsqrtf((float)(cnt[i] + 1));   // +1 self loop
}

// exclusive scan, stage 1: per-block (1024 elements) partial scan + block sums
__global__ void scan1_k(const int* __restrict__ in, int* __restrict__ part,
                        int* __restrict__ bsums, int n) {
    __shared__ int wsum[4];
    __shared__ int woff[4];
    int t = threadIdx.x;
    int base = blockIdx.x * 1024 + t * 4;
    int v0 = 0, v1 = 0, v2 = 0, v3 = 0;
    if (base + 3 < n) {
        v0 = in[base]; v1 = in[base + 1]; v2 = in[base + 2]; v3 = in[base + 3];
    } else {
        if (base     < n) v0 = in[base];
        if (base + 1 < n) v1 = in[base + 1];
        if (base + 2 < n) v2 = in[base + 2];
    }
    int s = v0 + v1 + v2 + v3;
    int lane = t & 63, wid = t >> 6;
    int x = s;
    #pragma unroll
    for (int d = 1; d < 64; d <<= 1) {
        int y = __shfl_up(x, d, 64);
        if (lane >= d) x += y;
    }
    if (lane == 63) wsum[wid] = x;
    __syncthreads();
    if (t == 0) {
        int r = 0;
        for (int w = 0; w < 4; ++w) { woff[w] = r; r += wsum[w]; }
        bsums[blockIdx.x] = r;
    }
    __syncthreads();
    int ex = woff[wid] + (x - s);
    if (base     < n) part[base]     = ex;
    if (base + 1 < n) part[base + 1] = ex + v0;
    if (base + 2 < n) part[base + 2] = ex + v0 + v1;
    if (base + 3 < n) part[base + 3] = ex + v0 + v1 + v2;
}

// stage 2: scan the (<=128) block sums with one block of 128 threads
__global__ void scan2_k(const int* __restrict__ bsums, int* __restrict__ boffs, int nb) {
    __shared__ int wsum[2];
    __shared__ int woff2[2];
    int t = threadIdx.x;
    int v = (t < nb) ? bsums[t] : 0;
    int lane = t & 63, wid = t >> 6;
    int x = v;
    #pragma unroll
    for (int d = 1; d < 64; d <<= 1) {
        int y = __shfl_up(x, d, 64);
        if (lane >= d) x += y;
    }
    if (lane == 63) wsum[wid] = x;
    __syncthreads();
    if (t == 0) { woff2[0] = 0; woff2[1] = wsum[0]; }
    __syncthreads();
    int ex = woff2[wid] + (x - v);
    if (t < nb) boffs[t] = ex;
}

// stage 3: add block offsets in place; init cursor; write off[N]
__global__ void scan3_k(int* __restrict__ off, const int* __restrict__ boffs,
                        int* __restrict__ cursor, int n, int total) {
    int i = blockIdx.x * 256 + threadIdx.x;
    if (i < n) {
        int v = off[i] + boffs[i >> 10];
        off[i] = v;
        cursor[i] = v;
    }
    if (i == 0) off[n] = total;
}

__global__ void fill_k(const int* __restrict__ srcA, const int* __restrict__ dstA,
                       const float* __restrict__ dinv, int* __restrict__ cursor,
                       int* __restrict__ csrc, float* __restrict__ cw) {
    int e = blockIdx.x * 256 + threadIdx.x;   // grid exactly EE
    int s = srcA[e], d = dstA[e];
    int pos = atomicAdd(&cursor[d], 1);
    csrc[pos] = s;
    cw[pos] = dinv[s] * dinv[d];
}

// ---------------- fused input-proj weight: Wc = W_in @ conv_W0, bc = b_in @ conv_W0 ----------------
__global__ void wc_k(const float* __restrict__ Win, const float* __restrict__ bin,
                     const float* __restrict__ cw0, float* __restrict__ Wc) {
    int idx = blockIdx.x * 256 + threadIdx.x;
    if (idx < NODE_DIM * HID) {
        int k = idx >> 6, c = idx & 63;
        float a = 0.f;
        #pragma unroll 8
        for (int j = 0; j < HID; ++j) a += Win[k * HID + j] * cw0[j * HID + c];
        Wc[idx] = a;
    } else if (idx < NODE_DIM * HID + HID) {
        int c = idx - NODE_DIM * HID;
        float a = 0.f;
        #pragma unroll 8
        for (int j = 0; j < HID; ++j) a += bin[j] * cw0[j * HID + c];
        Wc[idx] = a;
    }
}

// ---------------- transform: out[n,64] = in[n,K] @ W[K,64] (+bias) ----------------
// block = 256 threads = 4 waves; each wave handles 4 nodes; lane = output channel
template <int K, bool BIAS>
__global__ __launch_bounds__(256) void transform_k(const float* __restrict__ in,
                                                   const float* __restrict__ Wg,
                                                   const float* __restrict__ bias,
                                                   float* __restrict__ out) {
    __shared__ float Ws[K * HID];
    for (int idx = threadIdx.x; idx < K * HID; idx += 256) Ws[idx] = Wg[idx];
    __syncthreads();
    int lane = threadIdx.x & 63;
    int wid = threadIdx.x >> 6;
    int nbase = __builtin_amdgcn_readfirstlane((int)blockIdx.x * 16 + wid * 4);
    const float* r0 = in + (long)nbase * K;
    float a0 = 0.f, a1 = 0.f, a2 = 0.f, a3 = 0.f;
    #pragma unroll 8
    for (int k = 0; k < K; ++k) {
        float w = Ws[k * HID + lane];
        a0 += r0[k] * w;
        a1 += r0[K + k] * w;
        a2 += r0[2 * K + k] * w;
        a3 += r0[3 * K + k] * w;
    }
    if (BIAS) {
        float b = bias[lane];
        a0 += b; a1 += b; a2 += b; a3 += b;
    }
    long ob = (long)nbase * HID + lane;
    out[ob] = a0; out[ob + 64] = a1; out[ob + 128] = a2; out[ob + 192] = a3;
}

// ---------------- aggregate: out[i] = relu(BN(selfloop + sum_edges + conv_b)) ----------------
// one wave per node, lane = channel; epilogue applies conv_b + BN + ReLU
__global__ __launch_bounds__(256) void aggregate_k(const float* __restrict__ hw,
                                                   const int* __restrict__ off,
                                                   const int* __restrict__ src,
                                                   const float* __restrict__ ew,
                                                   const float* __restrict__ dinv,
                                                   const float* __restrict__ convb,
                                                   const float* __restrict__ gamma,
                                                   const float* __restrict__ beta,
                                                   const float* __restrict__ mean,
                                                   const float* __restrict__ var,
                                                   float* __restrict__ out) {
    int lane = threadIdx.x & 63;
    int i = __builtin_amdgcn_readfirstlane((int)blockIdx.x * 4 + (threadIdx.x >> 6));
    float sc = gamma[lane] * rsqrtf(var[lane] + BN_EPS);
    float sh = (convb[lane] - mean[lane]) * sc + beta[lane];
    float di = dinv[i];
    float acc = hw[(long)i * HID + lane] * di * di;   // self loop, norm = 1/deg
    int e0 = off[i], e1 = off[i + 1];
    for (int e = e0; e < e1; ++e) {
        int s = src[e];
        float w = ew[e];
        acc += hw[(long)s * HID + lane] * w;
    }
    float val = fmaxf(acc * sc + sh, 0.f);
    out[(long)i * HID + lane] = val;
}

// ---------------- pool (mean over sorted batch) + 3-layer MLP, one block per graph ----------------
__device__ __forceinline__ int lower_bound_i(const int* __restrict__ a, int n, int key) {
    int lo = 0, hi = n;
    while (lo < hi) {
        int m = (lo + hi) >> 1;
        if (a[m] < key) lo = m + 1; else hi = m;
    }
    return lo;
}

__global__ __launch_bounds__(64) void pool_mlp_k(const float* __restrict__ h,
                                                 const int* __restrict__ batch,
                                                 const float* __restrict__ W1, const float* __restrict__ b1,
                                                 const float* __restrict__ W2, const float* __restrict__ b2,
                                                 const float* __restrict__ W3, const float* __restrict__ b3,
                                                 float* __restrict__ out) {
    int g = blockIdx.x;
    int lane = threadIdx.x;
    int start = lower_bound_i(batch, NN, g);
    int end = lower_bound_i(batch, NN, g + 1);
    float acc = 0.f;
    for (int i = start; i < end; ++i) acc += h[(long)i * HID + lane];
    float cnt = (float)(end - start);
    float gv = acc / fmaxf(cnt, 1.0f);

    __shared__ float gs[HID];
    __shared__ float h1s[HID];
    gs[lane] = gv;
    __syncthreads();

    float a1 = b1[lane];
    #pragma unroll 8
    for (int k = 0; k < HID; ++k) a1 += gs[k] * W1[k * HID + lane];
    a1 = fmaxf(a1, 0.f);
    h1s[lane] = a1;
    __syncthreads();

    float a2 = 0.f;
    if (lane < 32) {
        a2 = b2[lane];
        #pragma unroll 8
        for (int k = 0; k < HID; ++k) a2 += h1s[k] * W2[k * 32 + lane];
        a2 = fmaxf(a2, 0.f);
    }
    float p = (lane < 32) ? a2 * W3[lane] : 0.f;
    #pragma unroll
    for (int d = 32; d >= 1; d >>= 1) p += __shfl_down(p, d, 64);
    if (lane == 0) out[g] = p + b3[0];
}

// ---------------- host launch ----------------
extern "C" void kernel_launch(void* const* d_in, const int* in_sizes, int n_in,
                              void* d_out, int out_size, void* d_ws, size_t ws_size,
                              hipStream_t stream) {
    (void)in_sizes; (void)n_in; (void)out_size; (void)ws_size;

    const float* x      = (const float*)d_in[0];
    const int*   eidx   = (const int*)d_in[1];      // [2,E]: src then dst
    const int*   batch  = (const int*)d_in[2];
    const float* W_in   = (const float*)d_in[3];
    const float* b_in   = (const float*)d_in[4];
    const float* conv_W = (const float*)d_in[5];    // [3,64,64]
    const float* conv_b = (const float*)d_in[6];    // [3,64]
    const float* gamma  = (const float*)d_in[7];
    const float* beta   = (const float*)d_in[8];
    const float* mean   = (const float*)d_in[9];
    const float* var    = (const float*)d_in[10];
    const float* W1     = (const float*)d_in[11];
    const float* b1     = (const float*)d_in[12];
    const float* W2     = (const float*)d_in[13];
    const float* b2     = (const float*)d_in[14];
    const float* W3     = (const float*)d_in[15];
    const float* b3     = (const float*)d_in[16];
    float* outp = (float*)d_out;

    int*   wsi = (int*)d_ws;
    float* wsf = (float*)d_ws;

    int*   deg    = wsi + I_DEG;
    int*   off    = wsi + I_OFF;
    int*   cur    = wsi + I_CUR;
    int*   bsums  = wsi + I_BS;
    int*   boffs  = wsi + I_BO;
    int*   csrc   = wsi + I_SRC;
    float* cw     = wsf + I_EW;
    float* dinv   = wsf + I_DINV;
    float* Wc     = wsf + I_WC;
    float* bufA   = wsf + I_BUFA;
    float* bufB   = wsf + I_BUFB;

    const int* esrc = eidx;
    const int* edst = eidx + EE;

    hipMemsetAsync(deg, 0, NN * sizeof(int), stream);

    count_k<<<EE / 256, 256, 0, stream>>>(edst, deg);
    dinv_k<<<(NN + 255) / 256, 256, 0, stream>>>(deg, dinv, NN);

    int nb = (NN + 1023) / 1024;   // 98
    scan1_k<<<nb, 256, 0, stream>>>(deg, off, bsums, NN);
    scan2_k<<<1, 128, 0, stream>>>(bsums, boffs, nb);
    scan3_k<<<(NN + 255) / 256, 256, 0, stream>>>(off, boffs, cur, NN, EE);

    wc_k<<<(NODE_DIM * HID + HID + 255) / 256, 256, 0, stream>>>(W_in, b_in, conv_W, Wc);
    fill_k<<<EE / 256, 256, 0, stream>>>(esrc, edst, dinv, cur, csrc, cw);

    // layer 0: fused input projection + conv transform
    transform_k<NODE_DIM, true><<<NN / 16, 256, 0, stream>>>(x, Wc, Wc + NODE_DIM * HID, bufA);
    aggregate_k<<<NN / 4, 256, 0, stream>>>(bufA, off, csrc, cw, dinv,
                                            conv_b + 0 * HID, gamma + 0 * HID, beta + 0 * HID,
                                            mean + 0 * HID, var + 0 * HID, bufB);
    // layer 1
    transform_k<HID, false><<<NN / 16, 256, 0, stream>>>(bufB, conv_W + 1 * HID * HID, nullptr, bufA);
    aggregate_k<<<NN / 4, 256, 0, stream>>>(bufA, off, csrc, cw, dinv,
                                            conv_b + 1 * HID, gamma + 1 * HID, beta + 1 * HID,
                                            mean + 1 * HID, var + 1 * HID, bufB);
    // layer 2
    transform_k<HID, false><<<NN / 16, 256, 0, stream>>>(bufB, conv_W + 2 * HID * HID, nullptr, bufA);
    aggregate_k<<<NN / 4, 256, 0, stream>>>(bufA, off, csrc, cw, dinv,
                                            conv_b + 2 * HID, gamma + 2 * HID, beta + 2 * HID,
                                            mean + 2 * HID, var + 2 * HID, bufB);

    // mean pool + MLP
    pool_mlp_k<<<NGRAPH, 64, 0, stream>>>(bufB, batch, W1, b1, W2, b2, W3, b3, outp);
}

// Round 2
// 679.598 us; speedup vs baseline: 1.1623x; 1.1623x over previous
//
#include <hip/hip_runtime.h>
#include <hip/hip_bf16.h>

// Problem constants (fixed by the reference)
#define NN 100000
#define EE 1600000
#define NODE_DIM 128
#define HID 64
#define NGRAPH 256
#define BN_EPS 1e-5f
#define NSLICE 8
#define SLICE_N 12500        // NN / NSLICE

// ---------------- workspace layout (units of 4 bytes) ----------------
#define I_DEG   0                         // int[NN]
#define I_OFF   100032                    // int[NN+1]
#define I_CUR   200064                    // int[NN]
#define I_BS    300096                    // int[128]
#define I_BO    300224                    // int[128]
#define I_SRC   300352                    // int[EE]
#define I_DINV  1900352                   // float[NN]
#define I_WC    2000352                   // float[128*64 + 64]
#define I_BUFA  2008608                   // float[NN*64]
#define I_BUFB  8408608                   // float[NN*64]
// total = 14,808,608 words = ~59.2 MB

// ---------------- graph prep ----------------

__global__ void count_k(const int* __restrict__ dst, int* __restrict__ cnt) {
    int e = blockIdx.x * 256 + threadIdx.x;   // grid exactly EE
    atomicAdd(&cnt[dst[e]], 1);
}

__global__ void dinv_k(const int* __restrict__ cnt, float* __restrict__ dinv, int n) {
    int i = blockIdx.x * 256 + threadIdx.x;
    if (i < n) dinv[i] = rsqrtf((float)(cnt[i] + 1));   // +1 self loop
}

// exclusive scan, stage 1: per-block (1024 elements) partial scan + block sums
__global__ void scan1_k(const int* __restrict__ in, int* __restrict__ part,
                        int* __restrict__ bsums, int n) {
    __shared__ int wsum[4];
    __shared__ int woff[4];
    int t = threadIdx.x;
    int base = blockIdx.x * 1024 + t * 4;
    int v0 = 0, v1 = 0, v2 = 0, v3 = 0;
    if (base + 3 < n) {
        v0 = in[base]; v1 = in[base + 1]; v2 = in[base + 2]; v3 = in[base + 3];
    } else {
        if (base     < n) v0 = in[base];
        if (base + 1 < n) v1 = in[base + 1];
        if (base + 2 < n) v2 = in[base + 2];
    }
    int s = v0 + v1 + v2 + v3;
    int lane = t & 63, wid = t >> 6;
    int x = s;
    #pragma unroll
    for (int d = 1; d < 64; d <<= 1) {
        int y = __shfl_up(x, d, 64);
        if (lane >= d) x += y;
    }
    if (lane == 63) wsum[wid] = x;
    __syncthreads();
    if (t == 0) {
        int r = 0;
        for (int w = 0; w < 4; ++w) { woff[w] = r; r += wsum[w]; }
        bsums[blockIdx.x] = r;
    }
    __syncthreads();
    int ex = woff[wid] + (x - s);
    if (base     < n) part[base]     = ex;
    if (base + 1 < n) part[base + 1] = ex + v0;
    if (base + 2 < n) part[base + 2] = ex + v0 + v1;
    if (base + 3 < n) part[base + 3] = ex + v0 + v1 + v2;
}

// stage 2: scan the (<=128) block sums with one block of 128 threads
__global__ void scan2_k(const int* __restrict__ bsums, int* __restrict__ boffs, int nb) {
    __shared__ int wsum[2];
    __shared__ int woff2[2];
    int t = threadIdx.x;
    int v = (t < nb) ? bsums[t] : 0;
    int lane = t & 63, wid = t >> 6;
    int x = v;
    #pragma unroll
    for (int d = 1; d < 64; d <<= 1) {
        int y = __shfl_up(x, d, 64);
        if (lane >= d) x += y;
    }
    if (lane == 63) wsum[wid] = x;
    __syncthreads();
    if (t == 0) { woff2[0] = 0; woff2[1] = wsum[0]; }
    __syncthreads();
    int ex = woff2[wid] + (x - v);
    if (t < nb) boffs[t] = ex;
}

// stage 3: add block offsets in place; init cursor; write off[N]
__global__ void scan3_k(int* __restrict__ off, const int* __restrict__ boffs,
                        int* __restrict__ cursor, int n, int total) {
    int i = blockIdx.x * 256 + threadIdx.x;
    if (i < n) {
        int v = off[i] + boffs[i >> 10];
        off[i] = v;
        cursor[i] = v;
    }
    if (i == 0) off[n] = total;
}

// XCD-sliced CSR fill: block (slice s = blockIdx&7, chunk c = blockIdx>>3)
// processes edges [c*2048, (c+1)*2048) whose dst falls in node slice s.
// With the round-robin block->XCD mapping, each CSR cache line is dirtied
// by exactly one XCD -> minimal write amplification.
__global__ __launch_bounds__(256) void fill_k(const int* __restrict__ srcA,
                                              const int* __restrict__ dstA,
                                              int* __restrict__ cursor,
                                              int* __restrict__ csrc) {
    int slice = blockIdx.x & 7;
    int chunk = blockIdx.x >> 3;
    int lo = slice * SLICE_N;
    int hi = lo + SLICE_N;
    int base = chunk * 2048 + threadIdx.x;
    #pragma unroll
    for (int j = 0; j < 8; ++j) {
        int e = base + j * 256;
        if (e < EE) {
            int d = dstA[e];
            if (d >= lo && d < hi) {
                int s = srcA[e];
                int pos = atomicAdd(&cursor[d], 1);
                csrc[pos] = s;
            }
        }
    }
}

// ---------------- fused input-proj weight: Wc = W_in @ conv_W0, bc = b_in @ conv_W0 ----------------
__global__ void wc_k(const float* __restrict__ Win, const float* __restrict__ bin,
                     const float* __restrict__ cw0, float* __restrict__ Wc) {
    int idx = blockIdx.x * 256 + threadIdx.x;
    if (idx < NODE_DIM * HID) {
        int k = idx >> 6, c = idx & 63;
        float a = 0.f;
        #pragma unroll 8
        for (int j = 0; j < HID; ++j) a += Win[k * HID + j] * cw0[j * HID + c];
        Wc[idx] = a;
    } else if (idx < NODE_DIM * HID + HID) {
        int c = idx - NODE_DIM * HID;
        float a = 0.f;
        #pragma unroll 8
        for (int j = 0; j < HID; ++j) a += bin[j] * cw0[j * HID + c];
        Wc[idx] = a;
    }
}

// ---------------- transform: out[n,64] = in[n,K] @ W[K,64] (+bias) ----------------
// block = 256 threads = 4 waves; each wave handles 4 nodes; lane = output channel
template <int K, bool BIAS>
__global__ __launch_bounds__(256) void transform_k(const float* __restrict__ in,
                                                   const float* __restrict__ Wg,
                                                   const float* __restrict__ bias,
                                                   float* __restrict__ out) {
    __shared__ float Ws[K * HID];
    for (int idx = threadIdx.x; idx < K * HID; idx += 256) Ws[idx] = Wg[idx];
    __syncthreads();
    int lane = threadIdx.x & 63;
    int wid = threadIdx.x >> 6;
    int nbase = __builtin_amdgcn_readfirstlane((int)blockIdx.x * 16 + wid * 4);
    const float* r0 = in + (long)nbase * K;
    float a0 = 0.f, a1 = 0.f, a2 = 0.f, a3 = 0.f;
    #pragma unroll 8
    for (int k = 0; k < K; ++k) {
        float w = Ws[k * HID + lane];
        a0 += r0[k] * w;
        a1 += r0[K + k] * w;
        a2 += r0[2 * K + k] * w;
        a3 += r0[3 * K + k] * w;
    }
    if (BIAS) {
        float b = bias[lane];
        a0 += b; a1 += b; a2 += b; a3 += b;
    }
    long ob = (long)nbase * HID + lane;
    out[ob] = a0; out[ob + 64] = a1; out[ob + 128] = a2; out[ob + 192] = a3;
}

// ---------------- aggregate: out[i] = relu(BN(selfloop + sum_edges + conv_b)) ----------------
// one wave per node, lane = channel; weight recomputed from dinv (no cw array);
// edge loop unrolled x4 so 4 gathers are in flight per waitcnt.
__global__ __launch_bounds__(256) void aggregate_k(const float* __restrict__ hw,
                                                   const int* __restrict__ off,
                                                   const int* __restrict__ src,
                                                   const float* __restrict__ dinv,
                                                   const float* __restrict__ convb,
                                                   const float* __restrict__ gamma,
                                                   const float* __restrict__ beta,
                                                   const float* __restrict__ mean,
                                                   const float* __restrict__ var,
                                                   float* __restrict__ out) {
    int lane = threadIdx.x & 63;
    int i = __builtin_amdgcn_readfirstlane((int)blockIdx.x * 4 + (threadIdx.x >> 6));
    float sc = gamma[lane] * rsqrtf(var[lane] + BN_EPS);
    float sh = (convb[lane] - mean[lane]) * sc + beta[lane];
    float di = dinv[i];
    float acc0 = hw[(long)i * HID + lane] * di * di;   // self loop, norm = 1/deg
    float acc1 = 0.f, acc2 = 0.f, acc3 = 0.f;
    int e0 = off[i], e1 = off[i + 1];
    int e = e0;
    for (; e + 4 <= e1; e += 4) {
        int s0 = src[e], s1 = src[e + 1], s2 = src[e + 2], s3 = src[e + 3];
        float w0 = dinv[s0], w1 = dinv[s1], w2 = dinv[s2], w3 = dinv[s3];
        float h0 = hw[(long)s0 * HID + lane];
        float h1 = hw[(long)s1 * HID + lane];
        float h2 = hw[(long)s2 * HID + lane];
        float h3 = hw[(long)s3 * HID + lane];
        acc0 += h0 * (w0 * di);
        acc1 += h1 * (w1 * di);
        acc2 += h2 * (w2 * di);
        acc3 += h3 * (w3 * di);
    }
    for (; e < e1; ++e) {
        int s = src[e];
        acc0 += hw[(long)s * HID + lane] * (dinv[s] * di);
    }
    float acc = (acc0 + acc1) + (acc2 + acc3);
    float val = fmaxf(acc * sc + sh, 0.f);
    out[(long)i * HID + lane] = val;
}

// ---------------- pool (mean over sorted batch) + 3-layer MLP, one block per graph ----------------
__device__ __forceinline__ int lower_bound_i(const int* __restrict__ a, int n, int key) {
    int lo = 0, hi = n;
    while (lo < hi) {
        int m = (lo + hi) >> 1;
        if (a[m] < key) lo = m + 1; else hi = m;
    }
    return lo;
}

__global__ __launch_bounds__(64) void pool_mlp_k(const float* __restrict__ h,
                                                 const int* __restrict__ batch,
                                                 const float* __restrict__ W1, const float* __restrict__ b1,
                                                 const float* __restrict__ W2, const float* __restrict__ b2,
                                                 const float* __restrict__ W3, const float* __restrict__ b3,
                                                 float* __restrict__ out) {
    int g = blockIdx.x;
    int lane = threadIdx.x;
    int start = lower_bound_i(batch, NN, g);
    int end = lower_bound_i(batch, NN, g + 1);
    float acc = 0.f;
    for (int i = start; i < end; ++i) acc += h[(long)i * HID + lane];
    float cnt = (float)(end - start);
    float gv = acc / fmaxf(cnt, 1.0f);

    __shared__ float gs[HID];
    __shared__ float h1s[HID];
    gs[lane] = gv;
    __syncthreads();

    float a1 = b1[lane];
    #pragma unroll 8
    for (int k = 0; k < HID; ++k) a1 += gs[k] * W1[k * HID + lane];
    a1 = fmaxf(a1, 0.f);
    h1s[lane] = a1;
    __syncthreads();

    float a2 = 0.f;
    if (lane < 32) {
        a2 = b2[lane];
        #pragma unroll 8
        for (int k = 0; k < HID; ++k) a2 += h1s[k] * W2[k * 32 + lane];
        a2 = fmaxf(a2, 0.f);
    }
    float p = (lane < 32) ? a2 * W3[lane] : 0.f;
    #pragma unroll
    for (int d = 32; d >= 1; d >>= 1) p += __shfl_down(p, d, 64);
    if (lane == 0) out[g] = p + b3[0];
}

// ---------------- host launch ----------------
extern "C" void kernel_launch(void* const* d_in, const int* in_sizes, int n_in,
                              void* d_out, int out_size, void* d_ws, size_t ws_size,
                              hipStream_t stream) {
    (void)in_sizes; (void)n_in; (void)out_size; (void)ws_size;

    const float* x      = (const float*)d_in[0];
    const int*   eidx   = (const int*)d_in[1];      // [2,E]: src then dst
    const int*   batch  = (const int*)d_in[2];
    const float* W_in   = (const float*)d_in[3];
    const float* b_in   = (const float*)d_in[4];
    const float* conv_W = (const float*)d_in[5];    // [3,64,64]
    const float* conv_b = (const float*)d_in[6];    // [3,64]
    const float* gamma  = (const float*)d_in[7];
    const float* beta   = (const float*)d_in[8];
    const float* mean   = (const float*)d_in[9];
    const float* var    = (const float*)d_in[10];
    const float* W1     = (const float*)d_in[11];
    const float* b1     = (const float*)d_in[12];
    const float* W2     = (const float*)d_in[13];
    const float* b2     = (const float*)d_in[14];
    const float* W3     = (const float*)d_in[15];
    const float* b3     = (const float*)d_in[16];
    float* outp = (float*)d_out;

    int*   wsi = (int*)d_ws;
    float* wsf = (float*)d_ws;

    int*   deg    = wsi + I_DEG;
    int*   off    = wsi + I_OFF;
    int*   cur    = wsi + I_CUR;
    int*   bsums  = wsi + I_BS;
    int*   boffs  = wsi + I_BO;
    int*   csrc   = wsi + I_SRC;
    float* dinv   = wsf + I_DINV;
    float* Wc     = wsf + I_WC;
    float* bufA   = wsf + I_BUFA;
    float* bufB   = wsf + I_BUFB;

    const int* esrc = eidx;
    const int* edst = eidx + EE;

    hipMemsetAsync(deg, 0, NN * sizeof(int), stream);

    count_k<<<EE / 256, 256, 0, stream>>>(edst, deg);
    dinv_k<<<(NN + 255) / 256, 256, 0, stream>>>(deg, dinv, NN);

    int nb = (NN + 1023) / 1024;   // 98
    scan1_k<<<nb, 256, 0, stream>>>(deg, off, bsums, NN);
    scan2_k<<<1, 128, 0, stream>>>(bsums, boffs, nb);
    scan3_k<<<(NN + 255) / 256, 256, 0, stream>>>(off, boffs, cur, NN, EE);

    wc_k<<<(NODE_DIM * HID + HID + 255) / 256, 256, 0, stream>>>(W_in, b_in, conv_W, Wc);

    int nchunk = (EE + 2047) / 2048;            // 782
    fill_k<<<nchunk * NSLICE, 256, 0, stream>>>(esrc, edst, cur, csrc);

    // layer 0: fused input projection + conv transform
    transform_k<NODE_DIM, true><<<NN / 16, 256, 0, stream>>>(x, Wc, Wc + NODE_DIM * HID, bufA);
    aggregate_k<<<NN / 4, 256, 0, stream>>>(bufA, off, csrc, dinv,
                                            conv_b + 0 * HID, gamma + 0 * HID, beta + 0 * HID,
                                            mean + 0 * HID, var + 0 * HID, bufB);
    // layer 1
    transform_k<HID, false><<<NN / 16, 256, 0, stream>>>(bufB, conv_W + 1 * HID * HID, nullptr, bufA);
    aggregate_k<<<NN / 4, 256, 0, stream>>>(bufA, off, csrc, dinv,
                                            conv_b + 1 * HID, gamma + 1 * HID, beta + 1 * HID,
                                            mean + 1 * HID, var + 1 * HID, bufB);
    // layer 2
    transform_k<HID, false><<<NN / 16, 256, 0, stream>>>(bufB, conv_W + 2 * HID * HID, nullptr, bufA);
    aggregate_k<<<NN / 4, 256, 0, stream>>>(bufA, off, csrc, dinv,
                                            conv_b + 2 * HID, gamma + 2 * HID, beta + 2 * HID,
                                            mean + 2 * HID, var + 2 * HID, bufB);

    // mean pool + MLP
    pool_mlp_k<<<NGRAPH, 64, 0, stream>>>(bufB, batch, W1, b1, W2, b2, W3, b3, outp);
}

// Round 3
// 602.378 us; speedup vs baseline: 1.3113x; 1.1282x over previous
//
#include <hip/hip_runtime.h>
#include <hip/hip_bf16.h>

// Problem constants (fixed by the reference)
#define NN 100000
#define EE 1600000
#define NODE_DIM 128
#define HID 64
#define NGRAPH 256
#define BN_EPS 1e-5f
#define NSLICE 8
#define SLICE_N 12500        // NN / NSLICE

// ---------------- workspace layout (units of 4 bytes) ----------------
#define I_DEG   0                         // int[NN]
#define I_OFF   100032                    // int[NN+1]
#define I_CUR   200064                    // int[NN]
#define I_BS    300096                    // int[128]
#define I_BO    300224                    // int[128]
#define I_SRC   300352                    // int[EE]
#define I_DINV  1900352                   // float[NN]
#define I_WC    2000352                   // float[128*64 + 64]
#define I_BUFA  2008608                   // float[NN*64]
#define I_BUFB  8408608                   // float[NN*64]
#define I_SUMS  14808608                  // float[NGRAPH*HID]
// total = 14,824,992 words = ~59.3 MB

// ---------------- graph prep ----------------

__global__ void count_k(const int* __restrict__ dst, int* __restrict__ cnt) {
    int e = blockIdx.x * 256 + threadIdx.x;   // grid exactly EE
    atomicAdd(&cnt[dst[e]], 1);
}

__global__ void dinv_k(const int* __restrict__ cnt, float* __restrict__ dinv, int n) {
    int i = blockIdx.x * 256 + threadIdx.x;
    if (i < n) dinv[i] = rsqrtf((float)(cnt[i] + 1));   // +1 self loop
}

// exclusive scan, stage 1: per-block (1024 elements) partial scan + block sums
__global__ void scan1_k(const int* __restrict__ in, int* __restrict__ part,
                        int* __restrict__ bsums, int n) {
    __shared__ int wsum[4];
    __shared__ int woff[4];
    int t = threadIdx.x;
    int base = blockIdx.x * 1024 + t * 4;
    int v0 = 0, v1 = 0, v2 = 0, v3 = 0;
    if (base + 3 < n) {
        v0 = in[base]; v1 = in[base + 1]; v2 = in[base + 2]; v3 = in[base + 3];
    } else {
        if (base     < n) v0 = in[base];
        if (base + 1 < n) v1 = in[base + 1];
        if (base + 2 < n) v2 = in[base + 2];
    }
    int s = v0 + v1 + v2 + v3;
    int lane = t & 63, wid = t >> 6;
    int x = s;
    #pragma unroll
    for (int d = 1; d < 64; d <<= 1) {
        int y = __shfl_up(x, d, 64);
        if (lane >= d) x += y;
    }
    if (lane == 63) wsum[wid] = x;
    __syncthreads();
    if (t == 0) {
        int r = 0;
        for (int w = 0; w < 4; ++w) { woff[w] = r; r += wsum[w]; }
        bsums[blockIdx.x] = r;
    }
    __syncthreads();
    int ex = woff[wid] + (x - s);
    if (base     < n) part[base]     = ex;
    if (base + 1 < n) part[base + 1] = ex + v0;
    if (base + 2 < n) part[base + 2] = ex + v0 + v1;
    if (base + 3 < n) part[base + 3] = ex + v0 + v1 + v2;
}

// stage 2: scan the (<=128) block sums with one block of 128 threads
__global__ void scan2_k(const int* __restrict__ bsums, int* __restrict__ boffs, int nb) {
    __shared__ int wsum[2];
    __shared__ int woff2[2];
    int t = threadIdx.x;
    int v = (t < nb) ? bsums[t] : 0;
    int lane = t & 63, wid = t >> 6;
    int x = v;
    #pragma unroll
    for (int d = 1; d < 64; d <<= 1) {
        int y = __shfl_up(x, d, 64);
        if (lane >= d) x += y;
    }
    if (lane == 63) wsum[wid] = x;
    __syncthreads();
    if (t == 0) { woff2[0] = 0; woff2[1] = wsum[0]; }
    __syncthreads();
    int ex = woff2[wid] + (x - v);
    if (t < nb) boffs[t] = ex;
}

// stage 3: add block offsets in place; init cursor; write off[N]
__global__ void scan3_k(int* __restrict__ off, const int* __restrict__ boffs,
                        int* __restrict__ cursor, int n, int total) {
    int i = blockIdx.x * 256 + threadIdx.x;
    if (i < n) {
        int v = off[i] + boffs[i >> 10];
        off[i] = v;
        cursor[i] = v;
    }
    if (i == 0) off[n] = total;
}

// XCD-sliced CSR fill (see round 1 notes): each CSR line dirtied by ~one XCD.
__global__ __launch_bounds__(256) void fill_k(const int* __restrict__ srcA,
                                              const int* __restrict__ dstA,
                                              int* __restrict__ cursor,
                                              int* __restrict__ csrc) {
    int slice = blockIdx.x & 7;
    int chunk = blockIdx.x >> 3;
    int lo = slice * SLICE_N;
    int hi = lo + SLICE_N;
    int base = chunk * 2048 + threadIdx.x;
    #pragma unroll
    for (int j = 0; j < 8; ++j) {
        int e = base + j * 256;
        if (e < EE) {
            int d = dstA[e];
            if (d >= lo && d < hi) {
                int s = srcA[e];
                int pos = atomicAdd(&cursor[d], 1);
                csrc[pos] = s;
            }
        }
    }
}

// ---------------- fused input-proj weight: Wc = W_in @ conv_W0, bc = b_in @ conv_W0 ----------------
__global__ void wc_k(const float* __restrict__ Win, const float* __restrict__ bin,
                     const float* __restrict__ cw0, float* __restrict__ Wc) {
    int idx = blockIdx.x * 256 + threadIdx.x;
    if (idx < NODE_DIM * HID) {
        int k = idx >> 6, c = idx & 63;
        float a = 0.f;
        #pragma unroll 8
        for (int j = 0; j < HID; ++j) a += Win[k * HID + j] * cw0[j * HID + c];
        Wc[idx] = a;
    } else if (idx < NODE_DIM * HID + HID) {
        int c = idx - NODE_DIM * HID;
        float a = 0.f;
        #pragma unroll 8
        for (int j = 0; j < HID; ++j) a += bin[j] * cw0[j * HID + c];
        Wc[idx] = a;
    }
}

// ---------------- transform: out[n,64] = in[n,K] @ W[K,64] (+bias) ----------------
template <int K, bool BIAS>
__global__ __launch_bounds__(256) void transform_k(const float* __restrict__ in,
                                                   const float* __restrict__ Wg,
                                                   const float* __restrict__ bias,
                                                   float* __restrict__ out) {
    __shared__ float Ws[K * HID];
    for (int idx = threadIdx.x; idx < K * HID; idx += 256) Ws[idx] = Wg[idx];
    __syncthreads();
    int lane = threadIdx.x & 63;
    int wid = threadIdx.x >> 6;
    int nbase = __builtin_amdgcn_readfirstlane((int)blockIdx.x * 16 + wid * 4);
    const float* r0 = in + (long)nbase * K;
    float a0 = 0.f, a1 = 0.f, a2 = 0.f, a3 = 0.f;
    #pragma unroll 8
    for (int k = 0; k < K; ++k) {
        float w = Ws[k * HID + lane];
        a0 += r0[k] * w;
        a1 += r0[K + k] * w;
        a2 += r0[2 * K + k] * w;
        a3 += r0[3 * K + k] * w;
    }
    if (BIAS) {
        float b = bias[lane];
        a0 += b; a1 += b; a2 += b; a3 += b;
    }
    long ob = (long)nbase * HID + lane;
    out[ob] = a0; out[ob + 64] = a1; out[ob + 128] = a2; out[ob + 192] = a3;
}

// ---------------- aggregate: out[i] = relu(BN(selfloop + sum_edges + conv_b)) ----------------
__global__ __launch_bounds__(256) void aggregate_k(const float* __restrict__ hw,
                                                   const int* __restrict__ off,
                                                   const int* __restrict__ src,
                                                   const float* __restrict__ dinv,
                                                   const float* __restrict__ convb,
                                                   const float* __restrict__ gamma,
                                                   const float* __restrict__ beta,
                                                   const float* __restrict__ mean,
                                                   const float* __restrict__ var,
                                                   float* __restrict__ out) {
    int lane = threadIdx.x & 63;
    int i = __builtin_amdgcn_readfirstlane((int)blockIdx.x * 4 + (threadIdx.x >> 6));
    float sc = gamma[lane] * rsqrtf(var[lane] + BN_EPS);
    float sh = (convb[lane] - mean[lane]) * sc + beta[lane];
    float di = dinv[i];
    float acc0 = hw[(long)i * HID + lane] * di * di;   // self loop, norm = 1/deg
    float acc1 = 0.f, acc2 = 0.f, acc3 = 0.f;
    int e0 = off[i], e1 = off[i + 1];
    int e = e0;
    for (; e + 4 <= e1; e += 4) {
        int s0 = src[e], s1 = src[e + 1], s2 = src[e + 2], s3 = src[e + 3];
        float w0 = dinv[s0], w1 = dinv[s1], w2 = dinv[s2], w3 = dinv[s3];
        float h0 = hw[(long)s0 * HID + lane];
        float h1 = hw[(long)s1 * HID + lane];
        float h2 = hw[(long)s2 * HID + lane];
        float h3 = hw[(long)s3 * HID + lane];
        acc0 += h0 * (w0 * di);
        acc1 += h1 * (w1 * di);
        acc2 += h2 * (w2 * di);
        acc3 += h3 * (w3 * di);
    }
    for (; e < e1; ++e) {
        int s = src[e];
        acc0 += hw[(long)s * HID + lane] * (dinv[s] * di);
    }
    float acc = (acc0 + acc1) + (acc2 + acc3);
    float val = fmaxf(acc * sc + sh, 0.f);
    out[(long)i * HID + lane] = val;
}

// ---------------- pooling stage 1: parallel segmented sum over sorted batch ----------------
// one wave per 64-node chunk, lane = channel; register accumulate, flush at
// graph boundaries via atomicAdd (sorted batch -> few boundaries per chunk).
__global__ __launch_bounds__(256) void pool1_k(const float* __restrict__ h,
                                               const int* __restrict__ batch,
                                               float* __restrict__ sums) {
    int lane = threadIdx.x & 63;
    int wid = threadIdx.x >> 6;
    int chunk = blockIdx.x * 4 + wid;
    int i0 = chunk * 64;
    if (i0 >= NN) return;
    int i1 = i0 + 64;
    if (i1 > NN) i1 = NN;
    int g = batch[i0];
    float acc = 0.f;
    for (int i = i0; i < i1; ++i) {
        int bi = batch[i];
        if (bi != g) {
            atomicAdd(&sums[g * HID + lane], acc);
            acc = 0.f;
            g = bi;
        }
        acc += h[(long)i * HID + lane];
    }
    atomicAdd(&sums[g * HID + lane], acc);
}

// ---------------- pooling stage 2 + 3-layer MLP, one block per graph ----------------
__device__ __forceinline__ int lower_bound_i(const int* __restrict__ a, int n, int key) {
    int lo = 0, hi = n;
    while (lo < hi) {
        int m = (lo + hi) >> 1;
        if (a[m] < key) lo = m + 1; else hi = m;
    }
    return lo;
}

__global__ __launch_bounds__(64) void mlp_k(const float* __restrict__ sums,
                                            const int* __restrict__ batch,
                                            const float* __restrict__ W1, const float* __restrict__ b1,
                                            const float* __restrict__ W2, const float* __restrict__ b2,
                                            const float* __restrict__ W3, const float* __restrict__ b3,
                                            float* __restrict__ out) {
    int g = blockIdx.x;
    int lane = threadIdx.x;
    int start = lower_bound_i(batch, NN, g);
    int end = lower_bound_i(batch, NN, g + 1);
    float cnt = (float)(end - start);
    float gv = sums[g * HID + lane] / fmaxf(cnt, 1.0f);

    __shared__ float gs[HID];
    __shared__ float h1s[HID];
    gs[lane] = gv;
    __syncthreads();

    float a1 = b1[lane];
    #pragma unroll 8
    for (int k = 0; k < HID; ++k) a1 += gs[k] * W1[k * HID + lane];
    a1 = fmaxf(a1, 0.f);
    h1s[lane] = a1;
    __syncthreads();

    float a2 = 0.f;
    if (lane < 32) {
        a2 = b2[lane];
        #pragma unroll 8
        for (int k = 0; k < HID; ++k) a2 += h1s[k] * W2[k * 32 + lane];
        a2 = fmaxf(a2, 0.f);
    }
    float p = (lane < 32) ? a2 * W3[lane] : 0.f;
    #pragma unroll
    for (int d = 32; d >= 1; d >>= 1) p += __shfl_down(p, d, 64);
    if (lane == 0) out[g] = p + b3[0];
}

// ---------------- host launch ----------------
extern "C" void kernel_launch(void* const* d_in, const int* in_sizes, int n_in,
                              void* d_out, int out_size, void* d_ws, size_t ws_size,
                              hipStream_t stream) {
    (void)in_sizes; (void)n_in; (void)out_size; (void)ws_size;

    const float* x      = (const float*)d_in[0];
    const int*   eidx   = (const int*)d_in[1];      // [2,E]: src then dst
    const int*   batch  = (const int*)d_in[2];
    const float* W_in   = (const float*)d_in[3];
    const float* b_in   = (const float*)d_in[4];
    const float* conv_W = (const float*)d_in[5];    // [3,64,64]
    const float* conv_b = (const float*)d_in[6];    // [3,64]
    const float* gamma  = (const float*)d_in[7];
    const float* beta   = (const float*)d_in[8];
    const float* mean   = (const float*)d_in[9];
    const float* var    = (const float*)d_in[10];
    const float* W1     = (const float*)d_in[11];
    const float* b1     = (const float*)d_in[12];
    const float* W2     = (const float*)d_in[13];
    const float* b2     = (const float*)d_in[14];
    const float* W3     = (const float*)d_in[15];
    const float* b3     = (const float*)d_in[16];
    float* outp = (float*)d_out;

    int*   wsi = (int*)d_ws;
    float* wsf = (float*)d_ws;

    int*   deg    = wsi + I_DEG;
    int*   off    = wsi + I_OFF;
    int*   cur    = wsi + I_CUR;
    int*   bsums  = wsi + I_BS;
    int*   boffs  = wsi + I_BO;
    int*   csrc   = wsi + I_SRC;
    float* dinv   = wsf + I_DINV;
    float* Wc     = wsf + I_WC;
    float* bufA   = wsf + I_BUFA;
    float* bufB   = wsf + I_BUFB;
    float* sums   = wsf + I_SUMS;

    const int* esrc = eidx;
    const int* edst = eidx + EE;

    hipMemsetAsync(deg, 0, NN * sizeof(int), stream);
    hipMemsetAsync(sums, 0, NGRAPH * HID * sizeof(float), stream);

    count_k<<<EE / 256, 256, 0, stream>>>(edst, deg);
    dinv_k<<<(NN + 255) / 256, 256, 0, stream>>>(deg, dinv, NN);

    int nb = (NN + 1023) / 1024;   // 98
    scan1_k<<<nb, 256, 0, stream>>>(deg, off, bsums, NN);
    scan2_k<<<1, 128, 0, stream>>>(bsums, boffs, nb);
    scan3_k<<<(NN + 255) / 256, 256, 0, stream>>>(off, boffs, cur, NN, EE);

    wc_k<<<(NODE_DIM * HID + HID + 255) / 256, 256, 0, stream>>>(W_in, b_in, conv_W, Wc);

    int nchunk = (EE + 2047) / 2048;            // 782
    fill_k<<<nchunk * NSLICE, 256, 0, stream>>>(esrc, edst, cur, csrc);

    // layer 0: fused input projection + conv transform
    transform_k<NODE_DIM, true><<<NN / 16, 256, 0, stream>>>(x, Wc, Wc + NODE_DIM * HID, bufA);
    aggregate_k<<<NN / 4, 256, 0, stream>>>(bufA, off, csrc, dinv,
                                            conv_b + 0 * HID, gamma + 0 * HID, beta + 0 * HID,
                                            mean + 0 * HID, var + 0 * HID, bufB);
    // layer 1
    transform_k<HID, false><<<NN / 16, 256, 0, stream>>>(bufB, conv_W + 1 * HID * HID, nullptr, bufA);
    aggregate_k<<<NN / 4, 256, 0, stream>>>(bufA, off, csrc, dinv,
                                            conv_b + 1 * HID, gamma + 1 * HID, beta + 1 * HID,
                                            mean + 1 * HID, var + 1 * HID, bufB);
    // layer 2
    transform_k<HID, false><<<NN / 16, 256, 0, stream>>>(bufB, conv_W + 2 * HID * HID, nullptr, bufA);
    aggregate_k<<<NN / 4, 256, 0, stream>>>(bufA, off, csrc, dinv,
                                            conv_b + 2 * HID, gamma + 2 * HID, beta + 2 * HID,
                                            mean + 2 * HID, var + 2 * HID, bufB);

    // mean pool (parallel) + MLP
    pool1_k<<<(NN / 64 + 3) / 4, 256, 0, stream>>>(bufB, batch, sums);
    mlp_k<<<NGRAPH, 64, 0, stream>>>(sums, batch, W1, b1, W2, b2, W3, b3, outp);
}